// Round 3
// baseline (831.277 us; speedup 1.0000x reference)
//
#include <hip/hip_runtime.h>
#include <hip/hip_bf16.h>

// Problem constants (match reference setup_inputs).
#define NN    100000
#define EE    1600000
#define DD    9
#define INF   128
#define OUTF  64
#define DOUT  (DD * OUTF)   // 576
#define NBINS (NN * DD)     // 900000 (dst,div) bins

typedef __bf16 bf16x8 __attribute__((ext_vector_type(8)));
typedef float  f32x4  __attribute__((ext_vector_type(4)));
typedef unsigned short us4 __attribute__((ext_vector_type(4)));

__device__ __forceinline__ unsigned short f32_to_bf16_rne(float f) {
    unsigned int u = __float_as_uint(f);
    unsigned int r = u + 0x7FFFu + ((u >> 16) & 1u);
    return (unsigned short)(r >> 16);
}

__device__ __forceinline__ float bf16_to_f32(unsigned short h) {
    return __uint_as_float(((unsigned int)h) << 16);
}

// ---- f32 -> bf16 bulk convert (for W only; feature cvt fused into gemm) ----
__global__ __launch_bounds__(256) void cvt_bf16_kernel(
    const float* __restrict__ in, unsigned short* __restrict__ out, int n4)
{
    int i = blockIdx.x * 256 + threadIdx.x;
    if (i < n4) {
        float4 v = reinterpret_cast<const float4*>(in)[i];
        ushort4 o;
        o.x = f32_to_bf16_rne(v.x);
        o.y = f32_to_bf16_rne(v.y);
        o.z = f32_to_bf16_rne(v.z);
        o.w = f32_to_bf16_rne(v.w);
        reinterpret_cast<ushort4*>(out)[i] = o;
    }
}

// ---- Wh[n][d][o] = (feature[n] . W[d][o]) * norm[n], bf16 out ----
// One block = 64 nodes (4 waves x 16). Feature fragments loaded ONCE (f32,
// converted in-register to bf16), then reused across all 9 divisions.
// A = W rows (m=channel), B = feature cols (n=node). C/D: col=lane&15 (node),
// row=quad*4+r (channel) -> lane stores 4 consecutive channels as ushort4.
__global__ __launch_bounds__(256) void gemm_wh_kernel(
    const float* __restrict__ feature,          // [N][128] f32
    const unsigned short* __restrict__ Wb,      // [D][64][128] bf16
    const float* __restrict__ norm,             // [N]
    unsigned short* __restrict__ Wh)            // [N][D*64] bf16
{
    const int wave = threadIdx.x >> 6;
    const int lane = threadIdx.x & 63;
    const int quad = lane >> 4;
    const int m16  = lane & 15;
    const int node = blockIdx.x * 64 + wave * 16 + m16;

    // B fragments: B[k=quad*8+j][n=lane&15] = feature[node][quad*8 + k*32 + j]
    bf16x8 bfrag[4];
    float nm = 0.0f;
    if (node < NN) {
        const float* fp = feature + (size_t)node * INF + quad * 8;
        #pragma unroll
        for (int k = 0; k < 4; ++k) {
            float4 lo = *reinterpret_cast<const float4*>(fp + k * 32);
            float4 hi = *reinterpret_cast<const float4*>(fp + k * 32 + 4);
            bf16x8 b;
            b[0] = (__bf16)lo.x; b[1] = (__bf16)lo.y; b[2] = (__bf16)lo.z; b[3] = (__bf16)lo.w;
            b[4] = (__bf16)hi.x; b[5] = (__bf16)hi.y; b[6] = (__bf16)hi.z; b[7] = (__bf16)hi.w;
            bfrag[k] = b;
        }
        nm = norm[node];
    } else {
        #pragma unroll
        for (int k = 0; k < 4; ++k) bfrag[k] = bf16x8{};
    }

    for (int d = 0; d < DD; ++d) {
        f32x4 acc[4] = {f32x4{0,0,0,0}, f32x4{0,0,0,0}, f32x4{0,0,0,0}, f32x4{0,0,0,0}};
        const unsigned short* wbase = Wb + (size_t)d * OUTF * INF;
        #pragma unroll
        for (int k = 0; k < 4; ++k) {
            #pragma unroll
            for (int f = 0; f < 4; ++f) {
                const bf16x8 afrag = *reinterpret_cast<const bf16x8*>(
                    wbase + (size_t)(f * 16 + m16) * INF + k * 32 + quad * 8);
                acc[f] = __builtin_amdgcn_mfma_f32_16x16x32_bf16(afrag, bfrag[k], acc[f], 0, 0, 0);
            }
        }
        if (node < NN) {
            unsigned short* o = Wh + (size_t)node * DOUT + d * OUTF + quad * 4;
            #pragma unroll
            for (int f = 0; f < 4; ++f) {
                us4 p;
                p[0] = f32_to_bf16_rne(acc[f][0] * nm);
                p[1] = f32_to_bf16_rne(acc[f][1] * nm);
                p[2] = f32_to_bf16_rne(acc[f][2] * nm);
                p[3] = f32_to_bf16_rne(acc[f][3] * nm);
                *reinterpret_cast<us4*>(o + f * 16) = p;
            }
        }
    }
}

// ---- CSR build: histogram over (dst*9+div) bins ----
__global__ __launch_bounds__(256) void hist_kernel(
    const int* __restrict__ dst, const int* __restrict__ ediv,
    int* __restrict__ count)
{
    int e = blockIdx.x * 256 + threadIdx.x;
    if (e < EE) atomicAdd(&count[dst[e] * DD + ediv[e]], 1);
}

// ---- segment allocation: disjoint bases via block scan + one cursor atomic ----
__global__ __launch_bounds__(256) void alloc_kernel(
    const int* __restrict__ count, int* __restrict__ basep,
    int* __restrict__ cur, int* __restrict__ cursor)
{
    __shared__ int wtot[4];
    __shared__ int bbase;
    const int lane = threadIdx.x & 63;
    const int wv   = threadIdx.x >> 6;
    const int g = blockIdx.x * 256 + threadIdx.x;
    const int c = (g < NBINS) ? count[g] : 0;
    int s = c;
    #pragma unroll
    for (int o = 1; o < 64; o <<= 1) {
        int t = __shfl_up(s, o);
        if (lane >= o) s += t;
    }
    if (lane == 63) wtot[wv] = s;
    __syncthreads();
    if (threadIdx.x == 0) {
        int t0 = wtot[0], t1 = wtot[1], t2 = wtot[2], t3 = wtot[3];
        bbase = atomicAdd(cursor, t0 + t1 + t2 + t3);
        wtot[0] = 0; wtot[1] = t0; wtot[2] = t0 + t1; wtot[3] = t0 + t1 + t2;
    }
    __syncthreads();
    int base = bbase + wtot[wv] + (s - c);
    if (g < NBINS) { basep[g] = base; cur[g] = base; }
}

// ---- fill: payload[slot] = src ----
__global__ __launch_bounds__(256) void fill_kernel(
    const int* __restrict__ src, const int* __restrict__ dst,
    const int* __restrict__ ediv, int* __restrict__ cur,
    int* __restrict__ payload)
{
    int e = blockIdx.x * 256 + threadIdx.x;
    if (e < EE) {
        int g = dst[e] * DD + ediv[e];
        int idx = atomicAdd(&cur[g], 1);
        payload[idx] = src[e];
    }
}

// ---- gather: one wave per bin; 4 groups of 16 lanes each own every 4th edge.
//      Group reads its edge's 128B Wh row as ushort4/lane; butterfly-reduce
//      across groups; lanes 0..15 write one coalesced float4 row. ----
__global__ __launch_bounds__(256) void gather_kernel(
    const unsigned short* __restrict__ Wh, const int* __restrict__ payload,
    const int* __restrict__ basep, const int* __restrict__ count,
    const float* __restrict__ norm, float* __restrict__ out)
{
    const int wv   = threadIdx.x >> 6;
    const int lane = threadIdx.x & 63;
    const int grp  = lane >> 4;
    const int l16  = lane & 15;
    const int g = blockIdx.x * 4 + wv;
    if (g >= NBINS) return;
    const int b = basep[g];
    const int c = count[g];
    const int n  = g / DD;
    const int dv = g - n * DD;

    float4 acc = {0.0f, 0.0f, 0.0f, 0.0f};
    for (int i = grp; i < c; i += 4) {
        int p = payload[b + i];
        us4 r = *reinterpret_cast<const us4*>(Wh + (size_t)p * DOUT + dv * OUTF + l16 * 4);
        acc.x += bf16_to_f32(r[0]);
        acc.y += bf16_to_f32(r[1]);
        acc.z += bf16_to_f32(r[2]);
        acc.w += bf16_to_f32(r[3]);
    }
    // combine the 4 groups (lane bits 4 and 5)
    acc.x += __shfl_xor(acc.x, 16); acc.y += __shfl_xor(acc.y, 16);
    acc.z += __shfl_xor(acc.z, 16); acc.w += __shfl_xor(acc.w, 16);
    acc.x += __shfl_xor(acc.x, 32); acc.y += __shfl_xor(acc.y, 32);
    acc.z += __shfl_xor(acc.z, 32); acc.w += __shfl_xor(acc.w, 32);

    if (grp == 0) {
        const float nm = norm[n];
        float4 v;
        v.x = fmaxf(acc.x * nm, 0.0f);
        v.y = fmaxf(acc.y * nm, 0.0f);
        v.z = fmaxf(acc.z * nm, 0.0f);
        v.w = fmaxf(acc.w * nm, 0.0f);
        *reinterpret_cast<float4*>(out + (size_t)n * DOUT + dv * OUTF + l16 * 4) = v;
    }
}

extern "C" void kernel_launch(void* const* d_in, const int* in_sizes, int n_in,
                              void* d_out, int out_size, void* d_ws, size_t ws_size,
                              hipStream_t stream) {
    const float* feature = (const float*)d_in[0];   // [N,128]
    const float* norm    = (const float*)d_in[1];   // [N,1]
    const float* W       = (const float*)d_in[2];   // [D,64,128]
    const int*   src     = (const int*)d_in[3];     // [E]
    const int*   dst     = (const int*)d_in[4];     // [E]
    const int*   ediv    = (const int*)d_in[5];     // [E]
    float* out = (float*)d_out;                     // [N, 576]

    // Workspace layout (~132.6 MB, fits the proven 141 MB budget):
    //   Wh      bf16 [N][576]     @ 0            (115,200,000 B)
    //   count   int  [NBINS]      @ 115,200,000  (3,600,000 B)
    //   basep   int  [NBINS]      @ 118,800,000
    //   cur     int  [NBINS]      @ 122,400,000
    //   payload int  [E]          @ 126,000,000  (6,400,000 B)
    //   cursor  int               @ 132,400,000
    //   Wb      bf16 [D][64][128] @ 132,400,064  (147,456 B)
    char* ws = (char*)d_ws;
    unsigned short* Wh = (unsigned short*)ws;
    int* count   = (int*)(ws + 115200000);
    int* basep   = (int*)(ws + 118800000);
    int* cur     = (int*)(ws + 122400000);
    int* payload = (int*)(ws + 126000000);
    int* cursor  = (int*)(ws + 132400000);
    unsigned short* Wb = (unsigned short*)(ws + 132400064);

    // 1) convert W to bf16 (tiny)
    const int nw4 = DD * OUTF * INF / 4; // 18,432
    cvt_bf16_kernel<<<(nw4 + 255) / 256, 256, 0, stream>>>(W, Wb, nw4);

    // 2) CSR build over (dst,div) bins
    hipMemsetAsync(count, 0, (size_t)NBINS * sizeof(int), stream);
    hipMemsetAsync(cursor, 0, sizeof(int), stream);
    hist_kernel<<<(EE + 255) / 256, 256, 0, stream>>>(dst, ediv, count);
    alloc_kernel<<<(NBINS + 255) / 256, 256, 0, stream>>>(count, basep, cur, cursor);
    fill_kernel<<<(EE + 255) / 256, 256, 0, stream>>>(src, dst, ediv, cur, payload);

    // 3) per-division projection (MFMA bf16), feature cvt + src-norm fused
    gemm_wh_kernel<<<(NN + 63) / 64, 256, 0, stream>>>(feature, Wb, norm, Wh);

    // 4) gather + fused dst-norm scale + relu
    gather_kernel<<<(NBINS + 3) / 4, 256, 0, stream>>>(Wh, payload, basep, count, norm, out);
}

// Round 4
// 735.279 us; speedup vs baseline: 1.1306x; 1.1306x over previous
//
#include <hip/hip_runtime.h>
#include <hip/hip_bf16.h>

// Problem constants (match reference setup_inputs).
#define NN    100000
#define EE    1600000
#define DD    9
#define INF   128
#define OUTF  64
#define DOUT  (DD * OUTF)   // 576

typedef __bf16 bf16x8 __attribute__((ext_vector_type(8)));
typedef float  f32x4  __attribute__((ext_vector_type(4)));
typedef unsigned short us4 __attribute__((ext_vector_type(4)));
typedef unsigned short us8 __attribute__((ext_vector_type(8)));

__device__ __forceinline__ unsigned short f32_to_bf16_rne(float f) {
    unsigned int u = __float_as_uint(f);
    unsigned int r = u + 0x7FFFu + ((u >> 16) & 1u);
    return (unsigned short)(r >> 16);
}

__device__ __forceinline__ float bf16_to_f32(unsigned short h) {
    return __uint_as_float(((unsigned int)h) << 16);
}

// ---- f32 -> bf16 bulk convert (W only) ----
__global__ __launch_bounds__(256) void cvt_bf16_kernel(
    const float* __restrict__ in, unsigned short* __restrict__ out, int n4)
{
    int i = blockIdx.x * 256 + threadIdx.x;
    if (i < n4) {
        float4 v = reinterpret_cast<const float4*>(in)[i];
        ushort4 o;
        o.x = f32_to_bf16_rne(v.x);
        o.y = f32_to_bf16_rne(v.y);
        o.z = f32_to_bf16_rne(v.z);
        o.w = f32_to_bf16_rne(v.w);
        reinterpret_cast<ushort4*>(out)[i] = o;
    }
}

// ---- Wh[n][d][o] = (feature[n]*norm[n]) . W[d][o], bf16 out ----
// grid = (ceil(N/64), 9). Block = 256 (4 waves x 16 nodes).
// Phase 1: coalesced float4 stage of 64x128 f32 feature tile -> bf16 LDS
//          (norm folded in). Rows padded to 136 shorts (conflict-free frags).
// Phase 2: MFMA, A = W rows (channel), B = feature cols (node) from LDS.
// Phase 3: C -> LDS transpose (rows padded to 72 shorts), then coalesced
//          global store: each inst = 8 full 128B lines of Wh.
__global__ __launch_bounds__(256) void gemm_wh_kernel(
    const float* __restrict__ feature,          // [N][128] f32
    const unsigned short* __restrict__ Wb,      // [D][64][128] bf16
    const float* __restrict__ norm,             // [N]
    unsigned short* __restrict__ Wh)            // [N][576] bf16
{
    __shared__ unsigned short lds[64 * 136];    // 17408 B; reused as [64][72] store buf
    const int d    = blockIdx.y;
    const int nb   = blockIdx.x * 64;
    const int tid  = threadIdx.x;
    const int wv   = tid >> 6;
    const int lane = tid & 63;
    const int quad = lane >> 4;
    const int m16  = lane & 15;

    // Phase 1: stage feature tile (coalesced), fold norm, convert to bf16
    const float* fb = feature + (size_t)nb * INF;
    #pragma unroll
    for (int it = 0; it < 4; ++it) {
        int chunk = it * 256 + tid;            // 0..1023 chunks of 8 floats
        int node = chunk >> 4;                 // 16 chunks per 128-wide row
        int seg  = chunk & 15;
        us8 o;
        if (nb + node < NN) {
            float nm = norm[nb + node];
            const float4* fp = reinterpret_cast<const float4*>(fb + (size_t)node * INF + seg * 8);
            float4 a = fp[0], b4 = fp[1];
            o[0] = f32_to_bf16_rne(a.x * nm);  o[1] = f32_to_bf16_rne(a.y * nm);
            o[2] = f32_to_bf16_rne(a.z * nm);  o[3] = f32_to_bf16_rne(a.w * nm);
            o[4] = f32_to_bf16_rne(b4.x * nm); o[5] = f32_to_bf16_rne(b4.y * nm);
            o[6] = f32_to_bf16_rne(b4.z * nm); o[7] = f32_to_bf16_rne(b4.w * nm);
        } else {
            o = us8{};
        }
        *reinterpret_cast<us8*>(&lds[node * 136 + seg * 8]) = o;
    }
    __syncthreads();

    // Phase 2: fragments + MFMA
    bf16x8 bfrag[4];
    {
        const unsigned short* rp = &lds[(wv * 16 + m16) * 136 + quad * 8];
        #pragma unroll
        for (int k = 0; k < 4; ++k)
            bfrag[k] = *reinterpret_cast<const bf16x8*>(rp + k * 32);
    }
    f32x4 acc[4] = {f32x4{0,0,0,0}, f32x4{0,0,0,0}, f32x4{0,0,0,0}, f32x4{0,0,0,0}};
    const unsigned short* wbase = Wb + (size_t)d * OUTF * INF;
    #pragma unroll
    for (int k = 0; k < 4; ++k) {
        #pragma unroll
        for (int f = 0; f < 4; ++f) {
            const bf16x8 afrag = *reinterpret_cast<const bf16x8*>(
                wbase + (size_t)(f * 16 + m16) * INF + k * 32 + quad * 8);
            acc[f] = __builtin_amdgcn_mfma_f32_16x16x32_bf16(afrag, bfrag[k], acc[f], 0, 0, 0);
        }
    }
    __syncthreads();   // everyone done reading feature LDS before overwrite

    // Phase 3a: C frags -> LDS store buffer [64][72]
    // C/D: col = m16 (node), row = quad*4 + r (+ f*16) = channel
    {
        unsigned short* sp = &lds[(wv * 16 + m16) * 72 + quad * 4];
        #pragma unroll
        for (int f = 0; f < 4; ++f) {
            us4 p;
            p[0] = f32_to_bf16_rne(acc[f][0]);
            p[1] = f32_to_bf16_rne(acc[f][1]);
            p[2] = f32_to_bf16_rne(acc[f][2]);
            p[3] = f32_to_bf16_rne(acc[f][3]);
            *reinterpret_cast<us4*>(sp + f * 16) = p;
        }
    }
    // Phase 3b: wave reads back its own 16 rows (in-wave LDS ordering, no sync)
    #pragma unroll
    for (int j = 0; j < 2; ++j) {
        int row = wv * 16 + j * 8 + (lane >> 3);
        int seg = lane & 7;
        us8 v = *reinterpret_cast<const us8*>(&lds[row * 72 + seg * 8]);
        int node = nb + row;
        if (node < NN)
            *reinterpret_cast<us8*>(Wh + (size_t)node * DOUT + d * OUTF + seg * 8) = v;
    }
}

// ---- CSR build: histogram over dst (N bins) ----
__global__ __launch_bounds__(256) void hist_kernel(
    const int* __restrict__ dst, int* __restrict__ count)
{
    int e = blockIdx.x * 256 + threadIdx.x;
    if (e < EE) atomicAdd(&count[dst[e]], 1);
}

// ---- segment allocation: disjoint bases via block scan + one cursor atomic ----
__global__ __launch_bounds__(256) void alloc_kernel(
    const int* __restrict__ count, int* __restrict__ basep, int* __restrict__ cursor)
{
    __shared__ int wtot[4];
    __shared__ int bbase;
    const int lane = threadIdx.x & 63;
    const int wv   = threadIdx.x >> 6;
    const int g = blockIdx.x * 256 + threadIdx.x;
    const int c = (g < NN) ? count[g] : 0;
    int s = c;
    #pragma unroll
    for (int o = 1; o < 64; o <<= 1) {
        int t = __shfl_up(s, o);
        if (lane >= o) s += t;
    }
    if (lane == 63) wtot[wv] = s;
    __syncthreads();
    if (threadIdx.x == 0) {
        int t0 = wtot[0], t1 = wtot[1], t2 = wtot[2], t3 = wtot[3];
        bbase = atomicAdd(cursor, t0 + t1 + t2 + t3);
        wtot[0] = 0; wtot[1] = t0; wtot[2] = t0 + t1; wtot[3] = t0 + t1 + t2;
    }
    __syncthreads();
    int base = bbase + wtot[wv] + (s - c);
    if (g < NN) basep[g] = base;
}

// ---- fill: payload[slot] = (src<<4)|div; slot via atomic bump of basep.
//      (gather recomputes original base as basep[n] - count[n]) ----
__global__ __launch_bounds__(256) void fill_kernel(
    const int* __restrict__ src, const int* __restrict__ dst,
    const int* __restrict__ ediv, int* __restrict__ basep,
    int* __restrict__ payload)
{
    int e = blockIdx.x * 256 + threadIdx.x;
    if (e < EE) {
        int idx = atomicAdd(&basep[dst[e]], 1);
        payload[idx] = (src[e] << 4) | ediv[e];
    }
}

// ---- gather: one wave per node; lane = channel. Wave loads <=64 packed
//      payloads in one coalesced read, broadcasts via readlane, keeps 8 row
//      loads in flight, accumulates into acc[9] (div is wave-uniform).
//      Epilogue: 9 coalesced 256B stores with fused dst-norm * relu. ----
__global__ __launch_bounds__(256) void gather_kernel(
    const unsigned short* __restrict__ Wh, const int* __restrict__ payload,
    const int* __restrict__ basep, const int* __restrict__ count,
    const float* __restrict__ norm, float* __restrict__ out)
{
    const int wv   = threadIdx.x >> 6;
    const int lane = threadIdx.x & 63;
    const int n = blockIdx.x * 4 + wv;
    if (n >= NN) return;
    const int c = count[n];
    const int b = basep[n] - c;   // fill bumped basep by exactly c

    float acc[DD];
    #pragma unroll
    for (int k = 0; k < DD; ++k) acc[k] = 0.0f;

    for (int i0 = 0; i0 < c; i0 += 64) {
        const int take = min(c - i0, 64);
        int pv = (lane < take) ? payload[b + i0 + lane] : 0;
        for (int j = 0; j < take; j += 8) {
            const int n8 = min(take - j, 8);
            float v[8];
            int dv[8];
            #pragma unroll
            for (int u = 0; u < 8; ++u) {
                if (u < n8) {
                    int p = __builtin_amdgcn_readlane(pv, j + u);
                    dv[u] = p & 15;
                    v[u] = bf16_to_f32(Wh[(size_t)(p >> 4) * DOUT + dv[u] * OUTF + lane]);
                }
            }
            #pragma unroll
            for (int u = 0; u < 8; ++u) {
                if (u < n8) {
                    #pragma unroll
                    for (int k = 0; k < DD; ++k) {
                        float m = (dv[u] == k) ? 1.0f : 0.0f;
                        acc[k] += m * v[u];
                    }
                }
            }
        }
    }

    const float nm = norm[n];
    #pragma unroll
    for (int k = 0; k < DD; ++k)
        out[(size_t)n * DOUT + k * OUTF + lane] = fmaxf(acc[k] * nm, 0.0f);
}

extern "C" void kernel_launch(void* const* d_in, const int* in_sizes, int n_in,
                              void* d_out, int out_size, void* d_ws, size_t ws_size,
                              hipStream_t stream) {
    const float* feature = (const float*)d_in[0];   // [N,128]
    const float* norm    = (const float*)d_in[1];   // [N,1]
    const float* W       = (const float*)d_in[2];   // [D,64,128]
    const int*   src     = (const int*)d_in[3];     // [E]
    const int*   dst     = (const int*)d_in[4];     // [E]
    const int*   ediv    = (const int*)d_in[5];     // [E]
    float* out = (float*)d_out;                     // [N, 576]

    // Workspace layout (~122.5 MB, well under the proven ~141 MB budget):
    //   Wh      bf16 [N][576]     @ 0            (115,200,000 B)
    //   count   int  [NN]         @ 115,200,000  (400,000 B)
    //   basep   int  [NN]         @ 115,600,000  (400,000 B)
    //   payload int  [E]          @ 116,000,000  (6,400,000 B)
    //   cursor  int               @ 122,400,000  (4 B)
    //   Wb      bf16 [D][64][128] @ 122,400,064  (147,456 B)
    char* ws = (char*)d_ws;
    unsigned short* Wh = (unsigned short*)ws;
    int* count   = (int*)(ws + 115200000);
    int* basep   = (int*)(ws + 115600000);
    int* payload = (int*)(ws + 116000000);
    int* cursor  = (int*)(ws + 122400000);
    unsigned short* Wb = (unsigned short*)(ws + 122400064);

    // 1) convert W to bf16 (tiny)
    const int nw4 = DD * OUTF * INF / 4; // 18,432
    cvt_bf16_kernel<<<(nw4 + 255) / 256, 256, 0, stream>>>(W, Wb, nw4);

    // 2) CSR build over dst bins
    hipMemsetAsync(count, 0, (size_t)NN * sizeof(int), stream);
    hipMemsetAsync(cursor, 0, sizeof(int), stream);
    hist_kernel<<<(EE + 255) / 256, 256, 0, stream>>>(dst, count);
    alloc_kernel<<<(NN + 255) / 256, 256, 0, stream>>>(count, basep, cursor);
    fill_kernel<<<(EE + 255) / 256, 256, 0, stream>>>(src, dst, ediv, basep, payload);

    // 3) per-division projection (MFMA bf16), feature cvt + src-norm fused
    dim3 g1((NN + 63) / 64, DD);
    gemm_wh_kernel<<<g1, 256, 0, stream>>>(feature, Wb, norm, Wh);

    // 4) gather + fused dst-norm scale + relu
    gather_kernel<<<(NN + 3) / 4, 256, 0, stream>>>(Wh, payload, basep, count, norm, out);
}